// Round 3
// baseline (185.049 us; speedup 1.0000x reference)
//
#include <hip/hip_runtime.h>
#include <math.h>

// Problem constants (fixed by setup_inputs): B=32, S=64, H=256.
#define EPSF 1e-8f
constexpr int B = 32;
constexpr int S = 64;
constexpr int H = 256;                 // floats per cell
constexpr int H4 = H / 4;              // float4 per cell = 64
constexpr int CELLS_PER_BATCH = S * S; // 4096
constexpr int CELLS = B * CELLS_PER_BATCH; // 131072
constexpr int CELLS_PER_WAVE = 32;     // mask window per wave (~11.2 active avg)
constexpr int NWAVES = CELLS / CELLS_PER_WAVE; // 4096 (1 wave per block)
constexpr int WAVES_PER_BATCH = CELLS_PER_BATCH / CELLS_PER_WAVE; // 128

// ws layout: float2 partial[wave] for wave in [0,4096)  (32 KB)
// Written non-atomically; no zeroing, no atomics, no prep kernel.

// pick up to 4 set bits out of rem (wave-uniform), return the g-th (-1 if none)
__device__ inline int pickg(unsigned& rem, int g) {
    int k = -1;
    #pragma unroll
    for (int i = 0; i < 4; ++i) {
        if (rem) {
            int kk = __ffs(rem) - 1;
            rem &= rem - 1;
            if (i == g) k = kk;
        }
    }
    return k;
}

// ---------------- kernel 1: main pass, mask-gated, 16-lane groups, A/B prefetch ----
// One wave per block owns 32 consecutive cells of one batch. Ballot the masks into
// a wave-uniform bitmask; each round assigns up to 4 active cells to the wave's
// four 16-lane groups. While the current round's dot/norm reduce+exp runs, the
// NEXT round's 4 cell-loads are already in flight (two named buffer sets A/B,
// explicitly unrolled so no register copies force a vmcnt drain).
__global__ __launch_bounds__(64) void main_kernel(const float* __restrict__ tmap,
                                                  const float* __restrict__ pq,
                                                  const int* __restrict__ mask_pos,
                                                  const int* __restrict__ mask_neg,
                                                  float* __restrict__ ws) {
    int lane = threadIdx.x;             // 0..63
    int wave = blockIdx.x;              // 0..4095
    int b = wave / WAVES_PER_BATCH;     // 0..31 (wave never straddles a batch)
    int waveBase = wave * CELLS_PER_WAVE;

    int p = lane & 15;   // position within 16-lane group
    int g = lane >> 4;   // group 0..3

    // q fragment: lane p holds q[4*(p+16m)..] for m=0..3 (same in all 4 groups)
    const float4* q4 = (const float4*)pq + (size_t)b * H4;
    float4 qm0 = q4[p], qm1 = q4[p + 16], qm2 = q4[p + 32], qm3 = q4[p + 48];

    // wave-local q-norm: ||q||^2 via within-group butterfly (identical per group)
    float ssq = qm0.x*qm0.x + qm0.y*qm0.y + qm0.z*qm0.z + qm0.w*qm0.w
              + qm1.x*qm1.x + qm1.y*qm1.y + qm1.z*qm1.z + qm1.w*qm1.w
              + qm2.x*qm2.x + qm2.y*qm2.y + qm2.z*qm2.z + qm2.w*qm2.w
              + qm3.x*qm3.x + qm3.y*qm3.y + qm3.z*qm3.z + qm3.w*qm3.w;
    #pragma unroll
    for (int off = 1; off <= 8; off <<= 1) ssq += __shfl_xor(ssq, off);
    float scale = (1.0f / (sqrtf(ssq) + EPSF)) * (1.0f / (1.0f + EPSF));

    // lanes 0..31 fetch this wave's mask words (128 B coalesced), ballot
    int mp = 0, mn = 0;
    if (lane < CELLS_PER_WAVE) {
        mp = mask_pos[waveBase + lane];
        mn = mask_neg[waveBase + lane];
    }
    unsigned bp = (unsigned)__ballot(mp != 0);
    unsigned bn = (unsigned)__ballot(mn != 0);
    unsigned act = bp | bn;   // wave-uniform; bits 0..31

    const float4* t4 = (const float4*)tmap;
    float wp = 0.0f, wn = 0.0f;

#define LOADC(kv, r0, r1, r2, r3)                                          \
    if (kv >= 0) {                                                         \
        const float4* cp = t4 + (size_t)(waveBase + kv) * H4 + p;          \
        r0 = cp[0]; r1 = cp[16]; r2 = cp[32]; r3 = cp[48];                 \
    }

#define PROCESS(kv, r0, r1, r2, r3)                                        \
    if (kv >= 0) {                                                         \
        float d  = r0.x*qm0.x + r0.y*qm0.y + r0.z*qm0.z + r0.w*qm0.w       \
                 + r1.x*qm1.x + r1.y*qm1.y + r1.z*qm1.z + r1.w*qm1.w       \
                 + r2.x*qm2.x + r2.y*qm2.y + r2.z*qm2.z + r2.w*qm2.w       \
                 + r3.x*qm3.x + r3.y*qm3.y + r3.z*qm3.z + r3.w*qm3.w;      \
        float ss = r0.x*r0.x + r0.y*r0.y + r0.z*r0.z + r0.w*r0.w           \
                 + r1.x*r1.x + r1.y*r1.y + r1.z*r1.z + r1.w*r1.w           \
                 + r2.x*r2.x + r2.y*r2.y + r2.z*r2.z + r2.w*r2.w           \
                 + r3.x*r3.x + r3.y*r3.y + r3.z*r3.z + r3.w*r3.w;          \
        _Pragma("unroll")                                                  \
        for (int off = 1; off <= 8; off <<= 1) {                           \
            d  += __shfl_xor(d, off);                                      \
            ss += __shfl_xor(ss, off);                                     \
        }                                                                  \
        float s = d * scale * rsqrtf(ss);                                  \
        float e = __expf(s);  /* TAO = 1 */                                \
        if ((bp >> kv) & 1) wp += e;                                       \
        if ((bn >> kv) & 1) wn += e;                                       \
    }

    if (act) {
        unsigned rem = act;
        float4 a0, a1, a2, a3, c0, c1, c2, c3;
        int kA = pickg(rem, g);          // rem!=0 => group 0 always assigned
        LOADC(kA, a0, a1, a2, a3)
        bool liveA = true;
        while (liveA) {
            bool liveB = (rem != 0);                 // wave-uniform
            int kB = liveB ? pickg(rem, g) : -1;
            LOADC(kB, c0, c1, c2, c3)                // B loads fly over A's reduce
            PROCESS(kA, a0, a1, a2, a3)
            liveA = (rem != 0);                      // wave-uniform
            kA = liveA ? pickg(rem, g) : -1;
            LOADC(kA, a0, a1, a2, a3)                // A' loads fly over B's reduce
            PROCESS(kB, c0, c1, c2, c3)
        }
    }
#undef LOADC
#undef PROCESS

    // combine the 4 groups (each group's 16 lanes hold identical wp/wn)
    wp += __shfl_xor(wp, 16); wp += __shfl_xor(wp, 32);
    wn += __shfl_xor(wn, 16); wn += __shfl_xor(wn, 32);
    if (lane == 0) ((float2*)ws)[wave] = make_float2(wp, wn);
}

// ---------------- kernel 2: reduce wave partials, per-batch loss, average ----------
__global__ __launch_bounds__(256) void final_kernel(const float* __restrict__ ws,
                                                    float* __restrict__ out) {
    const float2* pp = (const float2*)ws;
    int tid = threadIdx.x;
    int b = tid >> 3;              // 0..31 (aligned 8-lane cluster per batch)
    int h = tid & 7;
    float ep = 0.0f, en = 0.0f;
    #pragma unroll
    for (int m = 0; m < 16; ++m) { // partials b*128 + h + 8m cover all 128
        float2 v = pp[b * WAVES_PER_BATCH + h + 8 * m];
        ep += v.x; en += v.y;
    }
    #pragma unroll
    for (int off = 1; off <= 4; off <<= 1) {
        ep += __shfl_xor(ep, off);
        en += __shfl_xor(en, off);
    }
    __shared__ float2 acc[B];
    if (h == 0) acc[b] = make_float2(ep, en);
    __syncthreads();
    if (tid < B) {
        float2 a = acc[tid];
        float li = 0.0f; int v = 0;
        if (a.x > 0.0f && a.y > 0.0f) {  // == any(pos) && any(neg), since exp>0
            v = 1;
            li = -logf(a.x / (a.x + a.y + EPSF));
        }
        #pragma unroll
        for (int off = 16; off > 0; off >>= 1) {
            li += __shfl_xor(li, off);
            v  += __shfl_xor(v, off);
        }
        if (tid == 0) out[0] = li / (float)(v > 0 ? v : 1);
    }
}

extern "C" void kernel_launch(void* const* d_in, const int* in_sizes, int n_in,
                              void* d_out, int out_size, void* d_ws, size_t ws_size,
                              hipStream_t stream) {
    const float* pos_query = (const float*)d_in[0];  // (B,H) fp32
    const float* tmap      = (const float*)d_in[1];  // (B,S,S,H) fp32
    const int*   mask_pos  = (const int*)d_in[2];    // (B,S,S) bool -> int32
    const int*   mask_neg  = (const int*)d_in[3];
    float* out = (float*)d_out;
    float* ws  = (float*)d_ws;

    main_kernel<<<NWAVES, 64, 0, stream>>>(tmap, pos_query, mask_pos, mask_neg, ws);
    final_kernel<<<1, 256, 0, stream>>>(ws, out);
}